// Round 17
// baseline (481.871 us; speedup 1.0000x reference)
//
#include <hip/hip_runtime.h>

// VQ: B=16, C=D=256, H=64, W=64, K=1024
#define BB 16
#define CC 256
#define HH 64
#define WW 64
#define KK 1024
#define DD 256
#define HW (HH * WW)
#define TAU 0.0625f

typedef __attribute__((ext_vector_type(8))) short bf16x8;
typedef __attribute__((ext_vector_type(4))) float f32x4;

union Frag { bf16x8 v; unsigned int u[4]; };
union U4F  { uint4 u; bf16x8 v; };
__device__ inline bf16x8 asbf(const uint4 x) { U4F c; c.u = x; return c.v; }

// trunc-split 8 floats into bf16 hi/lo fragments (x = hi + lo + O(2^-16 x), Sterbenz-exact lo)
__device__ inline void split8r(const float4 a, const float4 b, Frag& hi, Frag& lo) {
    float f[8] = {a.x, a.y, a.z, a.w, b.x, b.y, b.z, b.w};
    #pragma unroll
    for (int p = 0; p < 4; ++p) {
        const unsigned int b0 = __float_as_uint(f[2 * p]), b1 = __float_as_uint(f[2 * p + 1]);
        const unsigned int h0 = b0 & 0xFFFF0000u, h1 = b1 & 0xFFFF0000u;
        const float r0 = f[2 * p]     - __uint_as_float(h0);
        const float r1 = f[2 * p + 1] - __uint_as_float(h1);
        hi.u[p] = (h0 >> 16) | h1;
        lo.u[p] = (__float_as_uint(r0) >> 16) | (__float_as_uint(r1) & 0xFFFF0000u);
    }
}

// Prep: codebook -> bf16 hi/lo in 16x16x32-fragment-linear uint4 layout + ehalf.
// (r16-validated, absmax 0.0)  ebt4[ct*1024 + ks*128 + term*64 + lane], lane = kq*16 + col:
//   code = ct*16 + col, k-dims = ks*32 + kq*8 .. +7.
__global__ __launch_bounds__(256) void vq_prep_kernel(const float* __restrict__ e,
                                                      float* __restrict__ ehalf,
                                                      uint4* __restrict__ ebt4) {
    const int gt = blockIdx.x * 256 + threadIdx.x;
    const int code = gt >> 3, ks = gt & 7;
    const int ct = code >> 4, col = code & 15;
    const float* src = e + (size_t)code * DD + ks * 32;
    float s = 0.0f;
    #pragma unroll
    for (int kq = 0; kq < 4; ++kq) {
        const float4 va = *reinterpret_cast<const float4*>(src + kq * 8);
        const float4 vb = *reinterpret_cast<const float4*>(src + kq * 8 + 4);
        Frag hi, lo;
        split8r(va, vb, hi, lo);
        const size_t base = (size_t)ct * 1024 + ks * 128 + kq * 16 + col;
        ebt4[base]      = make_uint4(hi.u[0], hi.u[1], hi.u[2], hi.u[3]);  // term 0
        ebt4[base + 64] = make_uint4(lo.u[0], lo.u[1], lo.u[2], lo.u[3]);  // term 1
        s += va.x * va.x + va.y * va.y + va.z * va.z + va.w * va.w
           + vb.x * vb.x + vb.y * vb.y + vb.z * vb.z + vb.w * vb.w;
    }
    #pragma unroll
    for (int off = 1; off < 8; off <<= 1) s += __shfl_xor(s, off, 64);  // 8 ks-threads/code
    if (ks == 0) ehalf[code] = 0.5f * s;
}

// Main: one block per (b,h) = 64 tokens; wave mg -> tokens mg*16..+15, ALL 1024 codes.
// A: 16 bf16x8 hi/lo frag-pairs in registers (64 VGPR).
// B: explicit DEPTH-1 double-buffered register prefetch (bh/bl[2][4], 64 VGPR):
//    each ks issues the NEXT group's 8 loads (incl. cross-pass) before the 12 MFMAs,
//    giving every load >=233 cyc of MFMA cover (~L2 latency).
// Inline exact-fp32 rescue for margin < TAU (r16-validated).
__global__ __launch_bounds__(256) void vq_mfma_kernel(
    const float* __restrict__ in, const float* __restrict__ emb,
    const float* __restrict__ ehalf, const uint4* __restrict__ ebt4,
    float* __restrict__ out) {

    __shared__ float eh_lds[KK];
    __shared__ int   idx_lds[64];
    __shared__ float xs[DD];
    __shared__ int   flags[64];
    __shared__ int   nflag;
    __shared__ float rv[4];
    __shared__ int   ri[4];

    const int tid = threadIdx.x;
    const int bid = blockIdx.x;
    const int b = bid >> 6, h = bid & 63;

    if (tid == 0) nflag = 0;
    for (int k = tid; k < KK; k += 256) eh_lds[k] = ehalf[k];

    const int lane = tid & 63;
    const int mg = tid >> 6;            // 4 waves x 16 tokens
    const int lr = lane & 15, lq = lane >> 4;
    const int w2 = mg * 16 + lr;        // A row token for this lane

    // ---- A fragments: 8 k-steps x (hi,lo), 64 VGPRs, loaded once ----
    bf16x8 ah[8], al[8];
    {
        const float* asrc = in + (size_t)b * CC * HW + (size_t)h * WW + w2;
        #pragma unroll
        for (int ks = 0; ks < 8; ++ks) {
            const int c0 = ks * 32 + lq * 8;
            float f[8];
            #pragma unroll
            for (int di = 0; di < 8; ++di) f[di] = asrc[(size_t)(c0 + di) * HW];
            Frag hi, lo;
            split8r(make_float4(f[0], f[1], f[2], f[3]),
                    make_float4(f[4], f[5], f[6], f[7]), hi, lo);
            ah[ks] = hi.v; al[ks] = lo.v;
        }
    }
    __syncthreads();   // eh_lds ready

    float bestv[4], best2[4]; int besti[4];
    #pragma unroll
    for (int r = 0; r < 4; ++r) { bestv[r] = -3.4e38f; best2[r] = -3.4e38f; besti[r] = 0; }

    // ---- K-loop: 16 passes x 4 code-tiles; depth-1 double-buffered B prefetch ----
    const uint4* bp = ebt4 + lane;      // pass-0 base (+lane)
    uint4 bh[2][4], bl[2][4];           // [parity][j] — indices compile-time after unroll
    #pragma unroll
    for (int j = 0; j < 4; ++j) {       // preload (pass 0, ks 0)
        bh[0][j] = bp[j * 1024];
        bl[0][j] = bp[j * 1024 + 64];
    }

    #pragma unroll 1
    for (int pass = 0; pass < 16; ++pass) {
        const uint4* bpn = (pass < 15) ? (bp + 4096) : (ebt4 + lane);  // next-pass base
        f32x4 acch[4], accl[4];
        #pragma unroll
        for (int j = 0; j < 4; ++j) {
            const float nh = -eh_lds[(pass * 4 + j) * 16 + lr];
            acch[j] = (f32x4){nh, nh, nh, nh};
            accl[j] = (f32x4){0.0f, 0.0f, 0.0f, 0.0f};
        }
        #pragma unroll
        for (int ks = 0; ks < 8; ++ks) {
            const int cur = ks & 1, nxt = cur ^ 1;
            // issue NEXT group's loads first (ks+1 of this pass, or ks 0 of next pass)
            const uint4* np = (ks < 7) ? (bp + (ks + 1) * 128) : bpn;
            #pragma unroll
            for (int j = 0; j < 4; ++j) {
                bh[nxt][j] = np[j * 1024];
                bl[nxt][j] = np[j * 1024 + 64];
            }
            // 12 MFMAs on the current (already-landed) group
            #pragma unroll
            for (int j = 0; j < 4; ++j)
                acch[j] = __builtin_amdgcn_mfma_f32_16x16x32_bf16(ah[ks], asbf(bh[cur][j]), acch[j], 0, 0, 0);
            #pragma unroll
            for (int j = 0; j < 4; ++j)
                accl[j] = __builtin_amdgcn_mfma_f32_16x16x32_bf16(al[ks], asbf(bh[cur][j]), accl[j], 0, 0, 0);
            #pragma unroll
            for (int j = 0; j < 4; ++j)
                acch[j] = __builtin_amdgcn_mfma_f32_16x16x32_bf16(ah[ks], asbf(bl[cur][j]), acch[j], 0, 0, 0);
        }
        #pragma unroll
        for (int j = 0; j < 4; ++j) {
            const int code = (pass * 4 + j) * 16 + lr;     // ascending per lane
            #pragma unroll
            for (int r = 0; r < 4; ++r) {
                const float v = acch[j][r] + accl[j][r];
                if (v > bestv[r]) { best2[r] = bestv[r]; bestv[r] = v; besti[r] = code; }
                else if (v > best2[r]) best2[r] = v;
            }
        }
        bp = bpn;
    }

    // ---- butterfly across the 16 code-columns (low 4 lane bits) ----
    #pragma unroll
    for (int m = 1; m < 16; m <<= 1) {
        #pragma unroll
        for (int r = 0; r < 4; ++r) {
            const float ob = __shfl_xor(bestv[r], m, 64);
            const float o2 = __shfl_xor(best2[r], m, 64);
            const int   oi = __shfl_xor(besti[r], m, 64);
            if (ob > bestv[r] || (ob == bestv[r] && oi < besti[r])) {
                best2[r] = fmaxf(bestv[r], o2); bestv[r] = ob; besti[r] = oi;
            } else {
                best2[r] = fmaxf(best2[r], ob);
            }
        }
    }
    if (lr == 0) {
        #pragma unroll
        for (int r = 0; r < 4; ++r) {
            const int tok = mg * 16 + lq * 4 + r;          // C/D row = lq*4 + r (r16-validated)
            idx_lds[tok] = besti[r];
            if (bestv[r] - best2[r] < TAU) { const int p = atomicAdd(&nflag, 1); flags[p] = tok; }
        }
    }
    __syncthreads();

    // ---- inline rescue: exact fp32 recompute for flagged tokens (r16-validated) ----
    const int nf = nflag;
    for (int f = 0; f < nf; ++f) {
        const int wf = flags[f];
        xs[tid] = in[(size_t)(b * CC + tid) * HW + (size_t)h * WW + wf];
        __syncthreads();
        float best = -3.4e38f; int bidx = 0;
        #pragma unroll
        for (int cc = 0; cc < 4; ++cc) {
            const int code = tid * 4 + cc;                 // ascending per thread
            float sc = -eh_lds[code];
            const float* er = emb + (size_t)code * DD;
            for (int d = 0; d < DD; d += 4) {
                sc = fmaf(xs[d + 0], er[d + 0], sc);
                sc = fmaf(xs[d + 1], er[d + 1], sc);
                sc = fmaf(xs[d + 2], er[d + 2], sc);
                sc = fmaf(xs[d + 3], er[d + 3], sc);
            }
            if (sc > best) { best = sc; bidx = code; }
        }
        #pragma unroll
        for (int m2 = 1; m2 < 64; m2 <<= 1) {
            const float ov = __shfl_xor(best, m2, 64);
            const int   oi = __shfl_xor(bidx, m2, 64);
            if (ov > best || (ov == best && oi < bidx)) { best = ov; bidx = oi; }
        }
        if ((tid & 63) == 0) { rv[tid >> 6] = best; ri[tid >> 6] = bidx; }
        __syncthreads();
        if (tid == 0) {
            float fbv = rv[0]; int fbi = ri[0];
            #pragma unroll
            for (int q = 1; q < 4; ++q)
                if (rv[q] > fbv || (rv[q] == fbv && ri[q] < fbi)) { fbv = rv[q]; fbi = ri[q]; }
            idx_lds[wf] = fbi;
        }
        __syncthreads();
    }

    // ---- epilogue: out = x + (q - x), coalesced over w (r16-validated) ----
    {
        const int w = tid & 63, cs = tid >> 6;
        const float* srcx = in + (size_t)b * CC * HW + (size_t)h * WW + w;
        float* dst = out + (size_t)b * CC * HW + (size_t)h * WW + w;
        const float* erow = emb + (size_t)idx_lds[w] * DD;
        #pragma unroll
        for (int c = cs; c < CC; c += 4) {
            const float x = srcx[(size_t)c * HW];
            const float q = erow[c];
            dst[(size_t)c * HW] = x + (q - x);
        }
    }
}

// ---- fallback path (validated fp32 VALU kernel) if ws is too small ----
__global__ __launch_bounds__(256) void vq_enorm_kernel(const float* __restrict__ e,
                                                       float* __restrict__ ehalf) {
    const int wave = threadIdx.x >> 6;
    const int lane = threadIdx.x & 63;
    const int k = blockIdx.x * 4 + wave;
    const float4 v = *reinterpret_cast<const float4*>(e + (size_t)k * DD + lane * 4);
    float s = v.x * v.x + v.y * v.y + v.z * v.z + v.w * v.w;
    #pragma unroll
    for (int off = 32; off; off >>= 1) s += __shfl_xor(s, off, 64);
    if (lane == 0) ehalf[k] = 0.5f * s;
}

__global__ __launch_bounds__(256) void vq_fallback_kernel(
    const float* __restrict__ in, const float* __restrict__ emb,
    const float* __restrict__ ehalf, float* __restrict__ out) {

    __shared__ float x_lds[64][260];
    __shared__ float red_v[64][16];
    __shared__ int   red_i[64][16];
    __shared__ int   idx_lds[64];

    const int tid = threadIdx.x;
    const int bid = blockIdx.x;
    const int b = bid >> 6, h = bid & 63;
    const int w = tid & 63, cs = tid >> 6;
    {
        const float* src = in + (size_t)b * CC * HW + (size_t)h * WW + w;
        #pragma unroll
        for (int c = cs; c < CC; c += 4) x_lds[w][c] = src[(size_t)c * HW];
    }
    __syncthreads();
    const int i = tid & 15;
    const int j = tid >> 4;
    float best_v[4]; int best_i[4];
    #pragma unroll
    for (int t = 0; t < 4; ++t) { best_v[t] = -3.4e38f; best_i[t] = 0; }
    for (int chunk = 0; chunk < KK; chunk += 128) {
        const int c0 = chunk + j * 8;
        const float* e0 = emb + (size_t)c0 * DD;
        float acc[4][8];
        #pragma unroll
        for (int cj = 0; cj < 8; ++cj) {
            const float nh = -ehalf[c0 + cj];
            #pragma unroll
            for (int t = 0; t < 4; ++t) acc[t][cj] = nh;
        }
        #pragma unroll 2
        for (int d = 0; d < DD; d += 4) {
            float4 xv[4], ev[8];
            #pragma unroll
            for (int t = 0; t < 4; ++t)
                xv[t] = *reinterpret_cast<const float4*>(&x_lds[i + 16 * t][d]);
            #pragma unroll
            for (int cj = 0; cj < 8; ++cj)
                ev[cj] = *reinterpret_cast<const float4*>(e0 + (size_t)cj * DD + d);
            #pragma unroll
            for (int t = 0; t < 4; ++t) {
                #pragma unroll
                for (int cj = 0; cj < 8; ++cj) {
                    float a = acc[t][cj];
                    a = fmaf(xv[t].x, ev[cj].x, a);
                    a = fmaf(xv[t].y, ev[cj].y, a);
                    a = fmaf(xv[t].z, ev[cj].z, a);
                    a = fmaf(xv[t].w, ev[cj].w, a);
                    acc[t][cj] = a;
                }
            }
        }
        #pragma unroll
        for (int cj = 0; cj < 8; ++cj)
            #pragma unroll
            for (int t = 0; t < 4; ++t)
                if (acc[t][cj] > best_v[t]) { best_v[t] = acc[t][cj]; best_i[t] = c0 + cj; }
    }
    #pragma unroll
    for (int t = 0; t < 4; ++t) { red_v[i + 16 * t][j] = best_v[t]; red_i[i + 16 * t][j] = best_i[t]; }
    __syncthreads();
    if (tid < 64) {
        float bv = red_v[tid][0]; int bi = red_i[tid][0];
        #pragma unroll
        for (int jj = 1; jj < 16; ++jj) {
            const float v = red_v[tid][jj]; const int id = red_i[tid][jj];
            if (v > bv || (v == bv && id < bi)) { bv = v; bi = id; }
        }
        idx_lds[tid] = bi;
    }
    __syncthreads();
    {
        float* dst = out + (size_t)b * CC * HW + (size_t)h * WW + w;
        const float* erow = emb + (size_t)idx_lds[w] * DD;
        #pragma unroll
        for (int c = cs; c < CC; c += 4) {
            const float x = x_lds[w][c];
            const float q = erow[c];
            dst[(size_t)c * HW] = x + (q - x);
        }
    }
}

extern "C" void kernel_launch(void* const* d_in, const int* in_sizes, int n_in,
                              void* d_out, int out_size, void* d_ws, size_t ws_size,
                              hipStream_t stream) {
    const float* in  = (const float*)d_in[0];
    const float* emb = (const float*)d_in[1];
    float* out = (float*)d_out;
    char* ws = (char*)d_ws;

    float* ehalf = (float*)ws;                                 // 4 KiB
    const size_t OFF_EBT = 4096;
    const size_t NEED = OFF_EBT + (size_t)KK * DD * 2 * 2;     // + 1 MiB

    if (ws_size < NEED) {
        vq_enorm_kernel<<<KK / 4, 256, 0, stream>>>(emb, ehalf);
        vq_fallback_kernel<<<BB * HH, 256, 0, stream>>>(in, emb, ehalf, out);
        return;
    }
    uint4* ebt4 = (uint4*)(ws + OFF_EBT);

    vq_prep_kernel<<<32, 256, 0, stream>>>(emb, ehalf, ebt4);
    vq_mfma_kernel<<<BB * HH, 256, 0, stream>>>(in, emb, ehalf, ebt4, out);
}

// Round 18
// 381.790 us; speedup vs baseline: 1.2621x; 1.2621x over previous
//
#include <hip/hip_runtime.h>

// VQ: B=16, C=D=256, H=64, W=64, K=1024
#define BB 16
#define CC 256
#define HH 64
#define WW 64
#define KK 1024
#define DD 256
#define HW (HH * WW)
#define TAU 0.0625f

typedef __attribute__((ext_vector_type(8))) short bf16x8;
typedef __attribute__((ext_vector_type(4))) float f32x4;

union Frag { bf16x8 v; unsigned int u[4]; };
union U4F  { uint4 u; bf16x8 v; };
__device__ inline bf16x8 asbf(const uint4 x) { U4F c; c.u = x; return c.v; }

__device__ inline void gld16(const void* g, void* l) {   // r8-validated
    __builtin_amdgcn_global_load_lds(
        (const __attribute__((address_space(1))) unsigned int*)g,
        (__attribute__((address_space(3))) unsigned int*)l, 16, 0, 0);
}

// trunc-split 8 floats into bf16 hi/lo fragments (x = hi + lo + O(2^-16 x), Sterbenz-exact lo)
__device__ inline void split8r(const float4 a, const float4 b, Frag& hi, Frag& lo) {
    float f[8] = {a.x, a.y, a.z, a.w, b.x, b.y, b.z, b.w};
    #pragma unroll
    for (int p = 0; p < 4; ++p) {
        const unsigned int b0 = __float_as_uint(f[2 * p]), b1 = __float_as_uint(f[2 * p + 1]);
        const unsigned int h0 = b0 & 0xFFFF0000u, h1 = b1 & 0xFFFF0000u;
        const float r0 = f[2 * p]     - __uint_as_float(h0);
        const float r1 = f[2 * p + 1] - __uint_as_float(h1);
        hi.u[p] = (h0 >> 16) | h1;
        lo.u[p] = (__float_as_uint(r0) >> 16) | (__float_as_uint(r1) & 0xFFFF0000u);
    }
}

// Prep: codebook -> bf16 hi/lo in 16x16x32-fragment-linear uint4 layout + ehalf.
// (r16-validated)  ebt4[ct*1024 + ks*128 + term*64 + lane], lane = kq*16 + col.
__global__ __launch_bounds__(256) void vq_prep_kernel(const float* __restrict__ e,
                                                      float* __restrict__ ehalf,
                                                      uint4* __restrict__ ebt4) {
    const int gt = blockIdx.x * 256 + threadIdx.x;
    const int code = gt >> 3, ks = gt & 7;
    const int ct = code >> 4, col = code & 15;
    const float* src = e + (size_t)code * DD + ks * 32;
    float s = 0.0f;
    #pragma unroll
    for (int kq = 0; kq < 4; ++kq) {
        const float4 va = *reinterpret_cast<const float4*>(src + kq * 8);
        const float4 vb = *reinterpret_cast<const float4*>(src + kq * 8 + 4);
        Frag hi, lo;
        split8r(va, vb, hi, lo);
        const size_t base = (size_t)ct * 1024 + ks * 128 + kq * 16 + col;
        ebt4[base]      = make_uint4(hi.u[0], hi.u[1], hi.u[2], hi.u[3]);
        ebt4[base + 64] = make_uint4(lo.u[0], lo.u[1], lo.u[2], lo.u[3]);
        s += va.x * va.x + va.y * va.y + va.z * va.z + va.w * va.w
           + vb.x * vb.x + vb.y * vb.y + vb.z * vb.z + vb.w * vb.w;
    }
    #pragma unroll
    for (int off = 1; off < 8; off <<= 1) s += __shfl_xor(s, off, 64);
    if (ks == 0) ehalf[code] = 0.5f * s;
}

// Main: one block per (b,h) = 64 tokens; wave mg -> tokens mg*16..+15, ALL 1024 codes.
// B staged through a 4-slot LDS ring (8 KB granules, shared by all 4 waves) via
// global_load_lds; counted vmcnt(4) + s_barrier per granule (r8-validated invariant:
// 3 granules = 6 loads/thread in flight, wrap-stage keeps it exact).
__global__ __launch_bounds__(256) void vq_mfma_kernel(
    const float* __restrict__ in, const float* __restrict__ emb,
    const float* __restrict__ ehalf, const uint4* __restrict__ ebt4,
    float* __restrict__ out) {

    __shared__ uint4 bb4[4][512];       // 32 KB B-granule ring
    __shared__ float eh_lds[KK];
    __shared__ int   idx_lds[64];
    __shared__ float xs[DD];
    __shared__ int   flags[64];
    __shared__ int   nflag;
    __shared__ float rv[4];
    __shared__ int   ri[4];

    const int tid = threadIdx.x;
    const int bid = blockIdx.x;
    const int b = bid >> 6, h = bid & 63;

    if (tid == 0) nflag = 0;
    for (int k = tid; k < KK; k += 256) eh_lds[k] = ehalf[k];

    const int lane = tid & 63;
    const int wv = tid >> 6;            // 4 waves x 16 tokens; also staging role (frag j = wv)
    const int lr = lane & 15, lq = lane >> 4;
    const int w2 = wv * 16 + lr;        // A row token for this lane

    // ---- A fragments: 8 k-steps x (hi,lo), 64 VGPRs (r16-validated) ----
    bf16x8 ah[8], al[8];
    {
        const float* asrc = in + (size_t)b * CC * HW + (size_t)h * WW + w2;
        #pragma unroll
        for (int ks = 0; ks < 8; ++ks) {
            const int c0 = ks * 32 + lq * 8;
            float f[8];
            #pragma unroll
            for (int di = 0; di < 8; ++di) f[di] = asrc[(size_t)(c0 + di) * HW];
            Frag hi, lo;
            split8r(make_float4(f[0], f[1], f[2], f[3]),
                    make_float4(f[4], f[5], f[6], f[7]), hi, lo);
            ah[ks] = hi.v; al[ks] = lo.v;
        }
    }
    __syncthreads();   // eh_lds ready; bb4 free

    // stage granule (PG, KG): wave wv stages frag j=wv, terms 0/1 -> slot KG&3
    #define STAGE_G(PG, KG) do { \
        const uint4* s_ = ebt4 + (size_t)(PG) * 4096 + wv * 1024 + (KG) * 128 + lane; \
        gld16(s_,      &bb4[(KG) & 3][(wv * 2 + 0) * 64]); \
        gld16(s_ + 64, &bb4[(KG) & 3][(wv * 2 + 1) * 64]); \
    } while (0)

    STAGE_G(0, 0); STAGE_G(0, 1); STAGE_G(0, 2);   // 6 loads/thread in flight

    float bestv[4], best2[4]; int besti[4];
    #pragma unroll
    for (int r = 0; r < 4; ++r) { bestv[r] = -3.4e38f; best2[r] = -3.4e38f; besti[r] = 0; }

    // ---- K-loop: 16 passes x 8 granules; LDS ring + counted vmcnt ----
    #pragma unroll 1
    for (int pass = 0; pass < 16; ++pass) {
        f32x4 acch[4], accl[4];
        #pragma unroll
        for (int j = 0; j < 4; ++j) {
            const float nh = -eh_lds[(pass * 4 + j) * 16 + lr];
            acch[j] = (f32x4){nh, nh, nh, nh};
            accl[j] = (f32x4){0.0f, 0.0f, 0.0f, 0.0f};
        }
        #pragma unroll
        for (int ks = 0; ks < 8; ++ks) {
            asm volatile("s_waitcnt vmcnt(4)" ::: "memory");   // granule s landed (ours)
            __builtin_amdgcn_s_barrier();                      // all waves' portions landed
            asm volatile("" ::: "memory");
            // stage granule s+3 (wrap mod 128); slot (ks+3)&3 was fully read at s-1
            {
                const int pg = (pass + ((ks + 3) >> 3)) & 15;
                const int kg = (ks + 3) & 7;
                STAGE_G(pg, kg);
            }
            // consume slot ks&3 (compile-time): 8 x ds_read_b128 + 12 MFMAs
            const uint4* gb = &bb4[ks & 3][0] + lane;
            uint4 bhu[4], blu[4];
            #pragma unroll
            for (int j = 0; j < 4; ++j) {
                bhu[j] = gb[j * 128];
                blu[j] = gb[j * 128 + 64];
            }
            #pragma unroll
            for (int j = 0; j < 4; ++j)
                acch[j] = __builtin_amdgcn_mfma_f32_16x16x32_bf16(ah[ks], asbf(bhu[j]), acch[j], 0, 0, 0);
            #pragma unroll
            for (int j = 0; j < 4; ++j)
                accl[j] = __builtin_amdgcn_mfma_f32_16x16x32_bf16(al[ks], asbf(bhu[j]), accl[j], 0, 0, 0);
            #pragma unroll
            for (int j = 0; j < 4; ++j)
                acch[j] = __builtin_amdgcn_mfma_f32_16x16x32_bf16(ah[ks], asbf(blu[j]), acch[j], 0, 0, 0);
        }
        #pragma unroll
        for (int j = 0; j < 4; ++j) {
            const int code = (pass * 4 + j) * 16 + lr;     // ascending per lane
            #pragma unroll
            for (int r = 0; r < 4; ++r) {
                const float v = acch[j][r] + accl[j][r];
                if (v > bestv[r]) { best2[r] = bestv[r]; bestv[r] = v; besti[r] = code; }
                else if (v > best2[r]) best2[r] = v;
            }
        }
    }
    #undef STAGE_G

    // ---- butterfly across the 16 code-columns (r16-validated) ----
    #pragma unroll
    for (int m = 1; m < 16; m <<= 1) {
        #pragma unroll
        for (int r = 0; r < 4; ++r) {
            const float ob = __shfl_xor(bestv[r], m, 64);
            const float o2 = __shfl_xor(best2[r], m, 64);
            const int   oi = __shfl_xor(besti[r], m, 64);
            if (ob > bestv[r] || (ob == bestv[r] && oi < besti[r])) {
                best2[r] = fmaxf(bestv[r], o2); bestv[r] = ob; besti[r] = oi;
            } else {
                best2[r] = fmaxf(best2[r], ob);
            }
        }
    }
    if (lr == 0) {
        #pragma unroll
        for (int r = 0; r < 4; ++r) {
            const int tok = wv * 16 + lq * 4 + r;          // C/D row = lq*4 + r
            idx_lds[tok] = besti[r];
            if (bestv[r] - best2[r] < TAU) { const int p = atomicAdd(&nflag, 1); flags[p] = tok; }
        }
    }
    __syncthreads();

    // ---- inline rescue: exact fp32 recompute for flagged tokens (r16-validated) ----
    const int nf = nflag;
    for (int f = 0; f < nf; ++f) {
        const int wf = flags[f];
        xs[tid] = in[(size_t)(b * CC + tid) * HW + (size_t)h * WW + wf];
        __syncthreads();
        float best = -3.4e38f; int bidx = 0;
        #pragma unroll
        for (int cc = 0; cc < 4; ++cc) {
            const int code = tid * 4 + cc;                 // ascending per thread
            float sc = -eh_lds[code];
            const float* er = emb + (size_t)code * DD;
            for (int d = 0; d < DD; d += 4) {
                sc = fmaf(xs[d + 0], er[d + 0], sc);
                sc = fmaf(xs[d + 1], er[d + 1], sc);
                sc = fmaf(xs[d + 2], er[d + 2], sc);
                sc = fmaf(xs[d + 3], er[d + 3], sc);
            }
            if (sc > best) { best = sc; bidx = code; }
        }
        #pragma unroll
        for (int m2 = 1; m2 < 64; m2 <<= 1) {
            const float ov = __shfl_xor(best, m2, 64);
            const int   oi = __shfl_xor(bidx, m2, 64);
            if (ov > best || (ov == best && oi < bidx)) { best = ov; bidx = oi; }
        }
        if ((tid & 63) == 0) { rv[tid >> 6] = best; ri[tid >> 6] = bidx; }
        __syncthreads();
        if (tid == 0) {
            float fbv = rv[0]; int fbi = ri[0];
            #pragma unroll
            for (int q = 1; q < 4; ++q)
                if (rv[q] > fbv || (rv[q] == fbv && ri[q] < fbi)) { fbv = rv[q]; fbi = ri[q]; }
            idx_lds[wf] = fbi;
        }
        __syncthreads();
    }

    // ---- epilogue: out = x + (q - x), coalesced over w (r16-validated) ----
    {
        const int w = tid & 63, cs = tid >> 6;
        const float* srcx = in + (size_t)b * CC * HW + (size_t)h * WW + w;
        float* dst = out + (size_t)b * CC * HW + (size_t)h * WW + w;
        const float* erow = emb + (size_t)idx_lds[w] * DD;
        #pragma unroll
        for (int c = cs; c < CC; c += 4) {
            const float x = srcx[(size_t)c * HW];
            const float q = erow[c];
            dst[(size_t)c * HW] = x + (q - x);
        }
    }
}

// ---- fallback path (validated fp32 VALU kernel) if ws is too small ----
__global__ __launch_bounds__(256) void vq_enorm_kernel(const float* __restrict__ e,
                                                       float* __restrict__ ehalf) {
    const int wave = threadIdx.x >> 6;
    const int lane = threadIdx.x & 63;
    const int k = blockIdx.x * 4 + wave;
    const float4 v = *reinterpret_cast<const float4*>(e + (size_t)k * DD + lane * 4);
    float s = v.x * v.x + v.y * v.y + v.z * v.z + v.w * v.w;
    #pragma unroll
    for (int off = 32; off; off >>= 1) s += __shfl_xor(s, off, 64);
    if (lane == 0) ehalf[k] = 0.5f * s;
}

__global__ __launch_bounds__(256) void vq_fallback_kernel(
    const float* __restrict__ in, const float* __restrict__ emb,
    const float* __restrict__ ehalf, float* __restrict__ out) {

    __shared__ float x_lds[64][260];
    __shared__ float red_v[64][16];
    __shared__ int   red_i[64][16];
    __shared__ int   idx_lds[64];

    const int tid = threadIdx.x;
    const int bid = blockIdx.x;
    const int b = bid >> 6, h = bid & 63;
    const int w = tid & 63, cs = tid >> 6;
    {
        const float* src = in + (size_t)b * CC * HW + (size_t)h * WW + w;
        #pragma unroll
        for (int c = cs; c < CC; c += 4) x_lds[w][c] = src[(size_t)c * HW];
    }
    __syncthreads();
    const int i = tid & 15;
    const int j = tid >> 4;
    float best_v[4]; int best_i[4];
    #pragma unroll
    for (int t = 0; t < 4; ++t) { best_v[t] = -3.4e38f; best_i[t] = 0; }
    for (int chunk = 0; chunk < KK; chunk += 128) {
        const int c0 = chunk + j * 8;
        const float* e0 = emb + (size_t)c0 * DD;
        float acc[4][8];
        #pragma unroll
        for (int cj = 0; cj < 8; ++cj) {
            const float nh = -ehalf[c0 + cj];
            #pragma unroll
            for (int t = 0; t < 4; ++t) acc[t][cj] = nh;
        }
        #pragma unroll 2
        for (int d = 0; d < DD; d += 4) {
            float4 xv[4], ev[8];
            #pragma unroll
            for (int t = 0; t < 4; ++t)
                xv[t] = *reinterpret_cast<const float4*>(&x_lds[i + 16 * t][d]);
            #pragma unroll
            for (int cj = 0; cj < 8; ++cj)
                ev[cj] = *reinterpret_cast<const float4*>(e0 + (size_t)cj * DD + d);
            #pragma unroll
            for (int t = 0; t < 4; ++t) {
                #pragma unroll
                for (int cj = 0; cj < 8; ++cj) {
                    float a = acc[t][cj];
                    a = fmaf(xv[t].x, ev[cj].x, a);
                    a = fmaf(xv[t].y, ev[cj].y, a);
                    a = fmaf(xv[t].z, ev[cj].z, a);
                    a = fmaf(xv[t].w, ev[cj].w, a);
                    acc[t][cj] = a;
                }
            }
        }
        #pragma unroll
        for (int cj = 0; cj < 8; ++cj)
            #pragma unroll
            for (int t = 0; t < 4; ++t)
                if (acc[t][cj] > best_v[t]) { best_v[t] = acc[t][cj]; best_i[t] = c0 + cj; }
    }
    #pragma unroll
    for (int t = 0; t < 4; ++t) { red_v[i + 16 * t][j] = best_v[t]; red_i[i + 16 * t][j] = best_i[t]; }
    __syncthreads();
    if (tid < 64) {
        float bv = red_v[tid][0]; int bi = red_i[tid][0];
        #pragma unroll
        for (int jj = 1; jj < 16; ++jj) {
            const float v = red_v[tid][jj]; const int id = red_i[tid][jj];
            if (v > bv || (v == bv && id < bi)) { bv = v; bi = id; }
        }
        idx_lds[tid] = bi;
    }
    __syncthreads();
    {
        float* dst = out + (size_t)b * CC * HW + (size_t)h * WW + w;
        const float* erow = emb + (size_t)idx_lds[w] * DD;
        #pragma unroll
        for (int c = cs; c < CC; c += 4) {
            const float x = x_lds[w][c];
            const float q = erow[c];
            dst[(size_t)c * HW] = x + (q - x);
        }
    }
}

extern "C" void kernel_launch(void* const* d_in, const int* in_sizes, int n_in,
                              void* d_out, int out_size, void* d_ws, size_t ws_size,
                              hipStream_t stream) {
    const float* in  = (const float*)d_in[0];
    const float* emb = (const float*)d_in[1];
    float* out = (float*)d_out;
    char* ws = (char*)d_ws;

    float* ehalf = (float*)ws;                                 // 4 KiB
    const size_t OFF_EBT = 4096;
    const size_t NEED = OFF_EBT + (size_t)KK * DD * 2 * 2;     // + 1 MiB

    if (ws_size < NEED) {
        vq_enorm_kernel<<<KK / 4, 256, 0, stream>>>(emb, ehalf);
        vq_fallback_kernel<<<BB * HH, 256, 0, stream>>>(in, emb, ehalf, out);
        return;
    }
    uint4* ebt4 = (uint4*)(ws + OFF_EBT);

    vq_prep_kernel<<<32, 256, 0, stream>>>(emb, ehalf, ebt4);
    vq_mfma_kernel<<<BB * HH, 256, 0, stream>>>(in, emb, ehalf, ebt4, out);
}

// Round 21
// 348.145 us; speedup vs baseline: 1.3841x; 1.0966x over previous
//
#include <hip/hip_runtime.h>

// VQ: B=16, C=D=256, H=64, W=64, K=1024
#define BB 16
#define CC 256
#define HH 64
#define WW 64
#define KK 1024
#define DD 256
#define HW (HH * WW)
#define TAU 0.0625f

typedef __attribute__((ext_vector_type(8))) short bf16x8;
typedef __attribute__((ext_vector_type(4))) float f32x4;

union Frag { bf16x8 v; unsigned int u[4]; };
union U4F  { uint4 u; bf16x8 v; };
__device__ inline bf16x8 asbf(const uint4 x) { U4F c; c.u = x; return c.v; }

__device__ inline void gld16(const void* g, void* l) {
    __builtin_amdgcn_global_load_lds(
        (const __attribute__((address_space(1))) unsigned int*)g,
        (__attribute__((address_space(3))) unsigned int*)l, 16, 0, 0);
}

// trunc-split 8 floats into bf16 hi/lo fragments (x = hi + lo + O(2^-16 x), Sterbenz-exact lo)
__device__ inline void split8r(const float4 a, const float4 b, Frag& hi, Frag& lo) {
    float f[8] = {a.x, a.y, a.z, a.w, b.x, b.y, b.z, b.w};
    #pragma unroll
    for (int p = 0; p < 4; ++p) {
        const unsigned int b0 = __float_as_uint(f[2 * p]), b1 = __float_as_uint(f[2 * p + 1]);
        const unsigned int h0 = b0 & 0xFFFF0000u, h1 = b1 & 0xFFFF0000u;
        const float r0 = f[2 * p]     - __uint_as_float(h0);
        const float r1 = f[2 * p + 1] - __uint_as_float(h1);
        hi.u[p] = (h0 >> 16) | h1;
        lo.u[p] = (__float_as_uint(r0) >> 16) | (__float_as_uint(r1) & 0xFFFF0000u);
    }
}

// Prep: codebook -> bf16 hi/lo in 16x16x32-fragment-linear uint4 layout + ehalf.
// (r16/r18-validated)  ebt4[ct*1024 + ks*128 + term*64 + lane], lane = kq*16 + col.
__global__ __launch_bounds__(256) void vq_prep_kernel(const float* __restrict__ e,
                                                      float* __restrict__ ehalf,
                                                      uint4* __restrict__ ebt4) {
    const int gt = blockIdx.x * 256 + threadIdx.x;
    const int code = gt >> 3, ks = gt & 7;
    const int ct = code >> 4, col = code & 15;
    const float* src = e + (size_t)code * DD + ks * 32;
    float s = 0.0f;
    #pragma unroll
    for (int kq = 0; kq < 4; ++kq) {
        const float4 va = *reinterpret_cast<const float4*>(src + kq * 8);
        const float4 vb = *reinterpret_cast<const float4*>(src + kq * 8 + 4);
        Frag hi, lo;
        split8r(va, vb, hi, lo);
        const size_t base = (size_t)ct * 1024 + ks * 128 + kq * 16 + col;
        ebt4[base]      = make_uint4(hi.u[0], hi.u[1], hi.u[2], hi.u[3]);
        ebt4[base + 64] = make_uint4(lo.u[0], lo.u[1], lo.u[2], lo.u[3]);
        s += va.x * va.x + va.y * va.y + va.z * va.z + va.w * va.w
           + vb.x * vb.x + vb.y * vb.y + vb.z * vb.z + vb.w * vb.w;
    }
    #pragma unroll
    for (int off = 1; off < 8; off <<= 1) s += __shfl_xor(s, off, 64);
    if (ks == 0) ehalf[code] = 0.5f * s;
}

// Main: one block per (b,h) = 64 tokens; wave wv -> tokens wv*16..+15, ALL 1024 codes.
// Half-pass double buffer (sizing bug in r19/r20 fixed): one half = 4 granules
// x 512 uint4 = 32 KB = one buffer. Per half: drain+barrier, stage next half into
// the other buffer (8 gld16/thread), compute 4 granules (32 ds_read_b128 + 48 MFMA).
__global__ __launch_bounds__(256) void vq_mfma_kernel(
    const float* __restrict__ in, const float* __restrict__ emb,
    const float* __restrict__ ehalf, const uint4* __restrict__ ebt4,
    float* __restrict__ out) {

    __shared__ uint4 bb4[2][2048];      // 2 x 32 KB half-pass buffers (4 granules x 512)
    __shared__ float eh_lds[KK];
    __shared__ int   idx_lds[64];
    __shared__ float xs[DD];
    __shared__ int   flags[64];
    __shared__ int   nflag;
    __shared__ float rv[4];
    __shared__ int   ri[4];

    const int tid = threadIdx.x;
    const int bid = blockIdx.x;
    const int b = bid >> 6, h = bid & 63;

    if (tid == 0) nflag = 0;
    for (int k = tid; k < KK; k += 256) eh_lds[k] = ehalf[k];

    const int lane = tid & 63;
    const int wv = tid >> 6;            // 4 waves x 16 tokens; staging role: frag j = wv
    const int lr = lane & 15, lq = lane >> 4;
    const int w2 = wv * 16 + lr;        // A row token for this lane

    // stage pass P, granules KB..KB+3 into BUF (granule stride 512 uint4 — frag j at
    // [kg*512 + j*128 .. +127], terms 0/1 at +0/+64). Dest is wave-uniform base.
    #define STAGE_HALF(P, KB, BUF) do { \
        _Pragma("unroll") \
        for (int kg_ = 0; kg_ < 4; ++kg_) { \
            const uint4* s_ = ebt4 + (size_t)(P) * 4096 + wv * 1024 + ((KB) + kg_) * 128 + lane; \
            gld16(s_,      &(BUF)[kg_ * 512 + wv * 128]); \
            gld16(s_ + 64, &(BUF)[kg_ * 512 + wv * 128 + 64]); \
        } \
    } while (0)

    STAGE_HALF(0, 0, bb4[0]);           // pass 0 first half; hides under A-load

    // ---- A fragments: 8 k-steps x (hi,lo), 64 VGPRs (r16-validated) ----
    bf16x8 ah[8], al[8];
    {
        const float* asrc = in + (size_t)b * CC * HW + (size_t)h * WW + w2;
        #pragma unroll
        for (int ks = 0; ks < 8; ++ks) {
            const int c0 = ks * 32 + lq * 8;
            float f[8];
            #pragma unroll
            for (int di = 0; di < 8; ++di) f[di] = asrc[(size_t)(c0 + di) * HW];
            Frag hi, lo;
            split8r(make_float4(f[0], f[1], f[2], f[3]),
                    make_float4(f[4], f[5], f[6], f[7]), hi, lo);
            ah[ks] = hi.v; al[ks] = lo.v;
        }
    }

    float bestv[4], best2[4]; int besti[4];
    #pragma unroll
    for (int r = 0; r < 4; ++r) { bestv[r] = -3.4e38f; best2[r] = -3.4e38f; besti[r] = 0; }

    // compute 4 granules from BUF with A-frag base KB
    #define COMPUTE_HALF(BUF, KB) do { \
        _Pragma("unroll") \
        for (int kg_ = 0; kg_ < 4; ++kg_) { \
            const uint4* gb_ = (BUF) + kg_ * 512 + lane; \
            uint4 bhu_[4], blu_[4]; \
            _Pragma("unroll") \
            for (int j_ = 0; j_ < 4; ++j_) { \
                bhu_[j_] = gb_[j_ * 128]; \
                blu_[j_] = gb_[j_ * 128 + 64]; \
            } \
            _Pragma("unroll") \
            for (int j_ = 0; j_ < 4; ++j_) \
                acch[j_] = __builtin_amdgcn_mfma_f32_16x16x32_bf16(ah[(KB) + kg_], asbf(bhu_[j_]), acch[j_], 0, 0, 0); \
            _Pragma("unroll") \
            for (int j_ = 0; j_ < 4; ++j_) \
                accl[j_] = __builtin_amdgcn_mfma_f32_16x16x32_bf16(al[(KB) + kg_], asbf(bhu_[j_]), accl[j_], 0, 0, 0); \
            _Pragma("unroll") \
            for (int j_ = 0; j_ < 4; ++j_) \
                acch[j_] = __builtin_amdgcn_mfma_f32_16x16x32_bf16(ah[(KB) + kg_], asbf(blu_[j_]), acch[j_], 0, 0, 0); \
        } \
    } while (0)

    // ---- K-loop: 16 passes x 2 halves; 48 MFMAs per drain+barrier ----
    #pragma unroll 1
    for (int pass = 0; pass < 16; ++pass) {
        f32x4 acch[4], accl[4];
        #pragma unroll
        for (int j = 0; j < 4; ++j) {
            const float nh = -eh_lds[(pass * 4 + j) * 16 + lr];
            acch[j] = (f32x4){nh, nh, nh, nh};
            accl[j] = (f32x4){0.0f, 0.0f, 0.0f, 0.0f};
        }
        // half 0: consume bb4[0] (granules 0..3); stage this pass's half 1 -> bb4[1]
        asm volatile("s_waitcnt vmcnt(0)" ::: "memory");
        __syncthreads();
        STAGE_HALF(pass, 4, bb4[1]);
        COMPUTE_HALF(bb4[0], 0);
        // half 1: consume bb4[1] (granules 4..7); stage next pass's half 0 -> bb4[0]
        asm volatile("s_waitcnt vmcnt(0)" ::: "memory");
        __syncthreads();
        if (pass < 15) STAGE_HALF(pass + 1, 0, bb4[0]);
        COMPUTE_HALF(bb4[1], 4);

        #pragma unroll
        for (int j = 0; j < 4; ++j) {
            const int code = (pass * 4 + j) * 16 + lr;     // ascending per lane
            #pragma unroll
            for (int r = 0; r < 4; ++r) {
                const float v = acch[j][r] + accl[j][r];
                if (v > bestv[r]) { best2[r] = bestv[r]; bestv[r] = v; besti[r] = code; }
                else if (v > best2[r]) best2[r] = v;
            }
        }
    }
    #undef COMPUTE_HALF
    #undef STAGE_HALF

    // ---- butterfly across the 16 code-columns (r16-validated) ----
    #pragma unroll
    for (int m = 1; m < 16; m <<= 1) {
        #pragma unroll
        for (int r = 0; r < 4; ++r) {
            const float ob = __shfl_xor(bestv[r], m, 64);
            const float o2 = __shfl_xor(best2[r], m, 64);
            const int   oi = __shfl_xor(besti[r], m, 64);
            if (ob > bestv[r] || (ob == bestv[r] && oi < besti[r])) {
                best2[r] = fmaxf(bestv[r], o2); bestv[r] = ob; besti[r] = oi;
            } else {
                best2[r] = fmaxf(best2[r], ob);
            }
        }
    }
    if (lr == 0) {
        #pragma unroll
        for (int r = 0; r < 4; ++r) {
            const int tok = wv * 16 + lq * 4 + r;          // C/D row = lq*4 + r
            idx_lds[tok] = besti[r];
            if (bestv[r] - best2[r] < TAU) { const int p = atomicAdd(&nflag, 1); flags[p] = tok; }
        }
    }
    __syncthreads();

    // ---- inline rescue: exact fp32 recompute for flagged tokens (r16-validated) ----
    const int nf = nflag;
    for (int f = 0; f < nf; ++f) {
        const int wf = flags[f];
        xs[tid] = in[(size_t)(b * CC + tid) * HW + (size_t)h * WW + wf];
        __syncthreads();
        float best = -3.4e38f; int bidx = 0;
        #pragma unroll
        for (int cc = 0; cc < 4; ++cc) {
            const int code = tid * 4 + cc;                 // ascending per thread
            float sc = -eh_lds[code];
            const float* er = emb + (size_t)code * DD;
            for (int d = 0; d < DD; d += 4) {
                sc = fmaf(xs[d + 0], er[d + 0], sc);
                sc = fmaf(xs[d + 1], er[d + 1], sc);
                sc = fmaf(xs[d + 2], er[d + 2], sc);
                sc = fmaf(xs[d + 3], er[d + 3], sc);
            }
            if (sc > best) { best = sc; bidx = code; }
        }
        #pragma unroll
        for (int m2 = 1; m2 < 64; m2 <<= 1) {
            const float ov = __shfl_xor(best, m2, 64);
            const int   oi = __shfl_xor(bidx, m2, 64);
            if (ov > best || (ov == best && oi < bidx)) { best = ov; bidx = oi; }
        }
        if ((tid & 63) == 0) { rv[tid >> 6] = best; ri[tid >> 6] = bidx; }
        __syncthreads();
        if (tid == 0) {
            float fbv = rv[0]; int fbi = ri[0];
            #pragma unroll
            for (int q = 1; q < 4; ++q)
                if (rv[q] > fbv || (rv[q] == fbv && ri[q] < fbi)) { fbv = rv[q]; fbi = ri[q]; }
            idx_lds[wf] = fbi;
        }
        __syncthreads();
    }

    // ---- epilogue: out = x + (q - x), coalesced over w (r16-validated) ----
    {
        const int w = tid & 63, cs = tid >> 6;
        const float* srcx = in + (size_t)b * CC * HW + (size_t)h * WW + w;
        float* dst = out + (size_t)b * CC * HW + (size_t)h * WW + w;
        const float* erow = emb + (size_t)idx_lds[w] * DD;
        #pragma unroll
        for (int c = cs; c < CC; c += 4) {
            const float x = srcx[(size_t)c * HW];
            const float q = erow[c];
            dst[(size_t)c * HW] = x + (q - x);
        }
    }
}

// ---- fallback path (validated fp32 VALU kernel) if ws is too small ----
__global__ __launch_bounds__(256) void vq_enorm_kernel(const float* __restrict__ e,
                                                       float* __restrict__ ehalf) {
    const int wave = threadIdx.x >> 6;
    const int lane = threadIdx.x & 63;
    const int k = blockIdx.x * 4 + wave;
    const float4 v = *reinterpret_cast<const float4*>(e + (size_t)k * DD + lane * 4);
    float s = v.x * v.x + v.y * v.y + v.z * v.z + v.w * v.w;
    #pragma unroll
    for (int off = 32; off; off >>= 1) s += __shfl_xor(s, off, 64);
    if (lane == 0) ehalf[k] = 0.5f * s;
}

__global__ __launch_bounds__(256) void vq_fallback_kernel(
    const float* __restrict__ in, const float* __restrict__ emb,
    const float* __restrict__ ehalf, float* __restrict__ out) {

    __shared__ float x_lds[64][260];
    __shared__ float red_v[64][16];
    __shared__ int   red_i[64][16];
    __shared__ int   idx_lds[64];

    const int tid = threadIdx.x;
    const int bid = blockIdx.x;
    const int b = bid >> 6, h = bid & 63;
    const int w = tid & 63, cs = tid >> 6;
    {
        const float* src = in + (size_t)b * CC * HW + (size_t)h * WW + w;
        #pragma unroll
        for (int c = cs; c < CC; c += 4) x_lds[w][c] = src[(size_t)c * HW];
    }
    __syncthreads();
    const int i = tid & 15;
    const int j = tid >> 4;
    float best_v[4]; int best_i[4];
    #pragma unroll
    for (int t = 0; t < 4; ++t) { best_v[t] = -3.4e38f; best_i[t] = 0; }
    for (int chunk = 0; chunk < KK; chunk += 128) {
        const int c0 = chunk + j * 8;
        const float* e0 = emb + (size_t)c0 * DD;
        float acc[4][8];
        #pragma unroll
        for (int cj = 0; cj < 8; ++cj) {
            const float nh = -ehalf[c0 + cj];
            #pragma unroll
            for (int t = 0; t < 4; ++t) acc[t][cj] = nh;
        }
        #pragma unroll 2
        for (int d = 0; d < DD; d += 4) {
            float4 xv[4], ev[8];
            #pragma unroll
            for (int t = 0; t < 4; ++t)
                xv[t] = *reinterpret_cast<const float4*>(&x_lds[i + 16 * t][d]);
            #pragma unroll
            for (int cj = 0; cj < 8; ++cj)
                ev[cj] = *reinterpret_cast<const float4*>(e0 + (size_t)cj * DD + d);
            #pragma unroll
            for (int t = 0; t < 4; ++t) {
                #pragma unroll
                for (int cj = 0; cj < 8; ++cj) {
                    float a = acc[t][cj];
                    a = fmaf(xv[t].x, ev[cj].x, a);
                    a = fmaf(xv[t].y, ev[cj].y, a);
                    a = fmaf(xv[t].z, ev[cj].z, a);
                    a = fmaf(xv[t].w, ev[cj].w, a);
                    acc[t][cj] = a;
                }
            }
        }
        #pragma unroll
        for (int cj = 0; cj < 8; ++cj)
            #pragma unroll
            for (int t = 0; t < 4; ++t)
                if (acc[t][cj] > best_v[t]) { best_v[t] = acc[t][cj]; best_i[t] = c0 + cj; }
    }
    #pragma unroll
    for (int t = 0; t < 4; ++t) { red_v[i + 16 * t][j] = best_v[t]; red_i[i + 16 * t][j] = best_i[t]; }
    __syncthreads();
    if (tid < 64) {
        float bv = red_v[tid][0]; int bi = red_i[tid][0];
        #pragma unroll
        for (int jj = 1; jj < 16; ++jj) {
            const float v = red_v[tid][jj]; const int id = red_i[tid][jj];
            if (v > bv || (v == bv && id < bi)) { bv = v; bi = id; }
        }
        idx_lds[tid] = bi;
    }
    __syncthreads();
    {
        float* dst = out + (size_t)b * CC * HW + (size_t)h * WW + w;
        const float* erow = emb + (size_t)idx_lds[w] * DD;
        #pragma unroll
        for (int c = cs; c < CC; c += 4) {
            const float x = x_lds[w][c];
            const float q = erow[c];
            dst[(size_t)c * HW] = x + (q - x);
        }
    }
}

extern "C" void kernel_launch(void* const* d_in, const int* in_sizes, int n_in,
                              void* d_out, int out_size, void* d_ws, size_t ws_size,
                              hipStream_t stream) {
    const float* in  = (const float*)d_in[0];
    const float* emb = (const float*)d_in[1];
    float* out = (float*)d_out;
    char* ws = (char*)d_ws;

    float* ehalf = (float*)ws;                                 // 4 KiB
    const size_t OFF_EBT = 4096;
    const size_t NEED = OFF_EBT + (size_t)KK * DD * 2 * 2;     // + 1 MiB

    if (ws_size < NEED) {
        vq_enorm_kernel<<<KK / 4, 256, 0, stream>>>(emb, ehalf);
        vq_fallback_kernel<<<BB * HH, 256, 0, stream>>>(in, emb, ehalf, out);
        return;
    }
    uint4* ebt4 = (uint4*)(ws + OFF_EBT);

    vq_prep_kernel<<<32, 256, 0, stream>>>(emb, ehalf, ebt4);
    vq_mfma_kernel<<<BB * HH, 256, 0, stream>>>(in, emb, ehalf, ebt4, out);
}